// Round 14
// baseline (800.253 us; speedup 1.0000x reference)
//
#include <hip/hip_runtime.h>

#define B_   4
#define T_   2048
#define BT_  8192
#define INL  15
#define DM   256
#define DI   512
#define DX   1024
#define DS_  16
#define DR_  16
#define NO_  48
#define NL   4
#define NC_  128
#define LCH  16

// k_init block partition: cvt blocks then inln blocks
#define N0C  (NL*DX*DM/4)
#define N1C  (NL*DM*DI/4)
#define N2C  (NL*NO_*DI/4)
#define NCVT ((N0C + N1C + N2C + DI + 255)/256)
#define NINL (BT_/4)
#define NCNT (3*128)

typedef short bf16x8 __attribute__((ext_vector_type(8)));
typedef float f32x4  __attribute__((ext_vector_type(4)));

__device__ __forceinline__ float sigmoidf_(float x){
    return __builtin_amdgcn_rcpf(1.f + __expf(-x));
}
__device__ __forceinline__ float softplusf_(float x){
    return fmaxf(x, 0.f) + __logf(1.f + __expf(-fabsf(x)));
}

__device__ __forceinline__ unsigned short f2bf(float x){
    union { float f; unsigned u; } v; v.f = x;
    unsigned r = (v.u + 0x7FFFu + ((v.u >> 16) & 1u)) >> 16;
    return (unsigned short)r;
}
__device__ __forceinline__ float bf2f(unsigned short h){
    union { unsigned u; float f; } v; v.u = ((unsigned)h) << 16;
    return v.f;
}

__device__ __forceinline__ void ld16(const float* __restrict__ p, float* v){
    const float4* q = (const float4*)p;
    float4 x0=q[0],x1=q[1],x2=q[2],x3=q[3];
    v[0]=x0.x; v[1]=x0.y; v[2]=x0.z; v[3]=x0.w;
    v[4]=x1.x; v[5]=x1.y; v[6]=x1.z; v[7]=x1.w;
    v[8]=x2.x; v[9]=x2.y; v[10]=x2.z; v[11]=x2.w;
    v[12]=x3.x; v[13]=x3.y; v[14]=x3.z; v[15]=x3.w;
}
__device__ __forceinline__ void st16(float* __restrict__ p, const float* v){
    float4* q = (float4*)p;
    q[0] = make_float4(v[0],v[1],v[2],v[3]);
    q[1] = make_float4(v[4],v[5],v[6],v[7]);
    q[2] = make_float4(v[8],v[9],v[10],v[11]);
    q[3] = make_float4(v[12],v[13],v[14],v[15]);
}

// ---- merged prologue: zero epilogue counters | weight cvt (+cw) | input GEMM + LN ----
__global__ void k_init(const float* __restrict__ W0, unsigned short* __restrict__ h0,
                       unsigned short* __restrict__ l0,
                       const float* __restrict__ W1, unsigned short* __restrict__ h1,
                       unsigned short* __restrict__ l1,
                       const float* __restrict__ W2, unsigned short* __restrict__ h2,
                       unsigned short* __restrict__ l2,
                       const float* __restrict__ opW3, const float* __restrict__ outW,
                       float* __restrict__ cwc,
                       const float* __restrict__ x, const float* __restrict__ W,
                       float* __restrict__ res,
                       unsigned short* __restrict__ hnhi, unsigned short* __restrict__ hnlo,
                       const float* __restrict__ w, const float* __restrict__ b,
                       unsigned* __restrict__ cnt){
    int bid = blockIdx.x;
    if(bid == 0){
        for(int i=threadIdx.x;i<NCNT;i+=256) cnt[i] = 0u;
    }
    if(bid < NCVT){
        int g = bid*256 + threadIdx.x;
        const float* Wp; unsigned short *hi, *lo; int idx;
        if(g < N0C){ Wp = W0; hi = h0; lo = l0; idx = g; }
        else if(g < N0C+N1C){ Wp = W1; hi = h1; lo = l1; idx = g - N0C; }
        else if(g < N0C+N1C+N2C){ Wp = W2; hi = h2; lo = l2; idx = g - N0C - N1C; }
        else {
            int k = g - (N0C+N1C+N2C);
            if(k < DI){
                float s = 0.f;
#pragma unroll 8
                for(int m=0;m<DM;m++) s += outW[m]*opW3[(size_t)m*DI + k];
                cwc[k] = s;
            }
            return;
        }
        float4 v = ((const float4*)Wp)[idx];
        ushort4 h, l;
        h.x = f2bf(v.x); l.x = f2bf(v.x - bf2f(h.x));
        h.y = f2bf(v.y); l.y = f2bf(v.y - bf2f(h.y));
        h.z = f2bf(v.z); l.z = f2bf(v.z - bf2f(h.z));
        h.w = f2bf(v.w); l.w = f2bf(v.w - bf2f(h.w));
        ((ushort4*)hi)[idx] = h;
        ((ushort4*)lo)[idx] = l;
        return;
    }
    // inln part
    int wv = threadIdx.x >> 6, lane = threadIdx.x & 63;
    int bt = (bid - NCVT)*4 + wv;
    const float* xr = x + bt*INL;
    float xl[INL];
#pragma unroll
    for(int k=0;k<INL;k++) xl[k] = xr[k];
    float4 v;
    float* vv = (float*)&v;
#pragma unroll
    for(int j=0;j<4;j++){
        int m = lane*4 + j;
        const float* wr = W + m*INL;
        float acc = 0.f;
#pragma unroll
        for(int k=0;k<INL;k++) acc += xl[k]*wr[k];
        vv[j] = acc;
    }
    ((float4*)(res + (size_t)bt*DM))[lane] = v;
    float s  = v.x+v.y+v.z+v.w;
    float ss = v.x*v.x+v.y*v.y+v.z*v.z+v.w*v.w;
#pragma unroll
    for(int m=1;m<64;m<<=1){ s += __shfl_xor(s,m); ss += __shfl_xor(ss,m); }
    float mean = s*(1.f/DM);
    float var  = ss*(1.f/DM) - mean*mean;
    float inv  = rsqrtf(var + 1e-5f);
    float4 wt = ((const float4*)w)[lane];
    float4 bs = ((const float4*)b)[lane];
    float4 o;
    o.x = (v.x-mean)*inv*wt.x + bs.x;
    o.y = (v.y-mean)*inv*wt.y + bs.y;
    o.z = (v.z-mean)*inv*wt.z + bs.z;
    o.w = (v.w-mean)*inv*wt.w + bs.w;
    ushort4 hh, ll;
    hh.x = f2bf(o.x); ll.x = f2bf(o.x - bf2f(hh.x));
    hh.y = f2bf(o.y); ll.y = f2bf(o.y - bf2f(hh.y));
    hh.z = f2bf(o.z); ll.z = f2bf(o.z - bf2f(hh.z));
    hh.w = f2bf(o.w); ll.w = f2bf(o.w - bf2f(hh.w));
    ((ushort4*)(hnhi + (size_t)bt*DM))[lane] = hh;
    ((ushort4*)(hnlo + (size_t)bt*DM))[lane] = ll;
}

// C[M][N] = A[M][K] @ Bw[N][K]^T via bf16 MFMA, hi/lo 3-term split (inproj)
template<int BM,int BN>
__global__ void __launch_bounds__(256) k_gemm_bf3(
    const unsigned short* __restrict__ Ahi, const unsigned short* __restrict__ Alo,
    const unsigned short* __restrict__ Bhi, const unsigned short* __restrict__ Blo,
    float* __restrict__ C, int M, int N, int K)
{
    constexpr int LDP = 40;
    constexpr int WM = BM/2, WN = BN/2;
    constexpr int MI_ = WM/16, NI_ = WN/16;
    __shared__ unsigned short sAh[BM*LDP], sAl[BM*LDP], sBh[BN*LDP], sBl[BN*LDP];
    int tid  = threadIdx.x;
    int wave = tid >> 6, lane = tid & 63;
    int wm0  = (wave >> 1) * WM, wn0 = (wave & 1) * WN;
    int m0   = blockIdx.y * BM, n0 = blockIdx.x * BN;
    int lr   = lane & 15;
    int kq   = (lane >> 4) * 8;
    int quad4 = (lane >> 4) * 4;

    f32x4 acc[MI_][NI_];
#pragma unroll
    for(int i=0;i<MI_;i++)
#pragma unroll
        for(int j=0;j<NI_;j++) acc[i][j] = (f32x4){0.f,0.f,0.f,0.f};

    for(int k0=0;k0<K;k0+=32){
#pragma unroll
        for(int i=tid;i<BM*4;i+=256){
            int r = i>>2, cg2 = (i&3)*8;
            size_t go = (size_t)(m0+r)*K + k0 + cg2;
            *(float4*)(&sAh[r*LDP + cg2]) = *(const float4*)(Ahi + go);
            *(float4*)(&sAl[r*LDP + cg2]) = *(const float4*)(Alo + go);
        }
#pragma unroll
        for(int i=tid;i<BN*4;i+=256){
            int r = i>>2, cg2 = (i&3)*8;
            size_t go = (size_t)(n0+r)*K + k0 + cg2;
            *(float4*)(&sBh[r*LDP + cg2]) = *(const float4*)(Bhi + go);
            *(float4*)(&sBl[r*LDP + cg2]) = *(const float4*)(Blo + go);
        }
        __syncthreads();
        bf16x8 ah[MI_], al[MI_], bh[NI_], bl[NI_];
#pragma unroll
        for(int mi=0;mi<MI_;mi++){
            int ro = (wm0 + mi*16 + lr)*LDP + kq;
            ah[mi] = *(const bf16x8*)(&sAh[ro]);
            al[mi] = *(const bf16x8*)(&sAl[ro]);
        }
#pragma unroll
        for(int ni=0;ni<NI_;ni++){
            int ro = (wn0 + ni*16 + lr)*LDP + kq;
            bh[ni] = *(const bf16x8*)(&sBh[ro]);
            bl[ni] = *(const bf16x8*)(&sBl[ro]);
        }
#pragma unroll
        for(int mi=0;mi<MI_;mi++)
#pragma unroll
            for(int ni=0;ni<NI_;ni++){
                acc[mi][ni] = __builtin_amdgcn_mfma_f32_16x16x32_bf16(ah[mi], bh[ni], acc[mi][ni], 0,0,0);
                acc[mi][ni] = __builtin_amdgcn_mfma_f32_16x16x32_bf16(ah[mi], bl[ni], acc[mi][ni], 0,0,0);
                acc[mi][ni] = __builtin_amdgcn_mfma_f32_16x16x32_bf16(al[mi], bh[ni], acc[mi][ni], 0,0,0);
            }
        __syncthreads();
    }
#pragma unroll
    for(int mi=0;mi<MI_;mi++)
#pragma unroll
        for(int ni=0;ni<NI_;ni++){
            int col = n0 + wn0 + ni*16 + lr;
#pragma unroll
            for(int r=0;r<4;r++){
                int row = m0 + wm0 + mi*16 + quad4 + r;
                C[(size_t)row*N + col] = acc[mi][ni][r];
            }
        }
}

// ---- outproj (layers 0..2): GEMM on packed Y, res += C; LAST n-block per m-tile
//      then runs the next layer's LN for its 64 rows (bit-identical to k_resln) ----
__global__ void __launch_bounds__(256) k_gemm_pk_res(
    const unsigned* __restrict__ Apk,
    const unsigned short* __restrict__ Bhi, const unsigned short* __restrict__ Blo,
    float* __restrict__ res,
    unsigned short* __restrict__ hnhi, unsigned short* __restrict__ hnlo,
    const float* __restrict__ nw, const float* __restrict__ nb,
    unsigned* __restrict__ cnt)
{
    constexpr int BM = 64, BN = 64, K = 512, LDP = 40;
    __shared__ unsigned short sAh[BM*LDP], sAl[BM*LDP], sBh[BN*LDP], sBl[BN*LDP];
    __shared__ unsigned sOld;
    int tid  = threadIdx.x;
    int wave = tid >> 6, lane = tid & 63;
    int wm0  = (wave >> 1) * 32, wn0 = (wave & 1) * 32;
    int m0   = blockIdx.y * BM, n0 = blockIdx.x * BN;
    int lr   = lane & 15;
    int kq   = (lane >> 4) * 8;
    int quad4 = (lane >> 4) * 4;

    f32x4 acc[2][2];
#pragma unroll
    for(int i=0;i<2;i++)
#pragma unroll
        for(int j=0;j<2;j++) acc[i][j] = (f32x4){0.f,0.f,0.f,0.f};

    for(int k0=0;k0<K;k0+=32){
        if(tid < BM*2){
            int r = tid>>1, hf = (tid&1)*16;
            const uint4* yp = (const uint4*)(Apk + (size_t)(m0+r)*K + k0 + hf);
#pragma unroll
            for(int q=0;q<4;q++){
                uint4 p = yp[q];
                ushort4 H, L;
                H.x=(unsigned short)p.x;  L.x=(unsigned short)(p.x>>16);
                H.y=(unsigned short)p.y;  L.y=(unsigned short)(p.y>>16);
                H.z=(unsigned short)p.z;  L.z=(unsigned short)(p.z>>16);
                H.w=(unsigned short)p.w;  L.w=(unsigned short)(p.w>>16);
                *(ushort4*)(&sAh[r*LDP + hf + q*4]) = H;
                *(ushort4*)(&sAl[r*LDP + hf + q*4]) = L;
            }
        }
        {
            int r = tid>>2, cg2 = (tid&3)*8;
            size_t go = (size_t)(n0+r)*K + k0 + cg2;
            *(float4*)(&sBh[r*LDP + cg2]) = *(const float4*)(Bhi + go);
            *(float4*)(&sBl[r*LDP + cg2]) = *(const float4*)(Blo + go);
        }
        __syncthreads();
        bf16x8 ah[2], al[2], bh[2], bl[2];
#pragma unroll
        for(int mi=0;mi<2;mi++){
            int ro = (wm0 + mi*16 + lr)*LDP + kq;
            ah[mi] = *(const bf16x8*)(&sAh[ro]);
            al[mi] = *(const bf16x8*)(&sAl[ro]);
        }
#pragma unroll
        for(int ni=0;ni<2;ni++){
            int ro = (wn0 + ni*16 + lr)*LDP + kq;
            bh[ni] = *(const bf16x8*)(&sBh[ro]);
            bl[ni] = *(const bf16x8*)(&sBl[ro]);
        }
#pragma unroll
        for(int mi=0;mi<2;mi++)
#pragma unroll
            for(int ni=0;ni<2;ni++){
                acc[mi][ni] = __builtin_amdgcn_mfma_f32_16x16x32_bf16(ah[mi], bh[ni], acc[mi][ni], 0,0,0);
                acc[mi][ni] = __builtin_amdgcn_mfma_f32_16x16x32_bf16(ah[mi], bl[ni], acc[mi][ni], 0,0,0);
                acc[mi][ni] = __builtin_amdgcn_mfma_f32_16x16x32_bf16(al[mi], bh[ni], acc[mi][ni], 0,0,0);
            }
        __syncthreads();
    }
    // epilogue: res += C (each (row,col) owned by exactly one thread)
#pragma unroll
    for(int mi=0;mi<2;mi++)
#pragma unroll
        for(int ni=0;ni<2;ni++){
            int col = n0 + wn0 + ni*16 + lr;
#pragma unroll
            for(int r=0;r<4;r++){
                int row = m0 + wm0 + mi*16 + quad4 + r;
                size_t o = (size_t)row*DM + col;
                res[o] += acc[mi][ni][r];
            }
        }
    // last n-block of this m-tile runs LN for rows m0..m0+63
    __threadfence();
    __syncthreads();
    if(tid == 0) sOld = atomicAdd(&cnt[blockIdx.y], 1u);
    __syncthreads();
    if(sOld == 3u){
        __threadfence();
#pragma unroll 2
        for(int rr=0;rr<16;rr++){
            int bt = m0 + wave*16 + rr;
            float4 v = ((const float4*)(res + (size_t)bt*DM))[lane];
            float s  = v.x+v.y+v.z+v.w;
            float ss = v.x*v.x+v.y*v.y+v.z*v.z+v.w*v.w;
#pragma unroll
            for(int m=1;m<64;m<<=1){ s += __shfl_xor(s,m); ss += __shfl_xor(ss,m); }
            float mean = s*(1.f/DM);
            float var  = ss*(1.f/DM) - mean*mean;
            float inv  = rsqrtf(var + 1e-5f);
            float4 wt = ((const float4*)nw)[lane];
            float4 bs = ((const float4*)nb)[lane];
            float4 o;
            o.x = (v.x-mean)*inv*wt.x + bs.x;
            o.y = (v.y-mean)*inv*wt.y + bs.y;
            o.z = (v.z-mean)*inv*wt.z + bs.z;
            o.w = (v.w-mean)*inv*wt.w + bs.w;
            ushort4 hh, ll;
            hh.x = f2bf(o.x); ll.x = f2bf(o.x - bf2f(hh.x));
            hh.y = f2bf(o.y); ll.y = f2bf(o.y - bf2f(hh.y));
            hh.z = f2bf(o.z); ll.z = f2bf(o.z - bf2f(hh.z));
            hh.w = f2bf(o.w); ll.w = f2bf(o.w - bf2f(hh.w));
            ((ushort4*)(hnhi + (size_t)bt*DM))[lane] = hh;
            ((ushort4*)(hnlo + (size_t)bt*DM))[lane] = ll;
        }
    }
}

// ---- conv+SiLU | xproj MFMA (B streamed from L2) | lean fused scan pass-1 ----
__global__ void __launch_bounds__(512) k_convxp2(
    const float* __restrict__ xz, const float* __restrict__ cw, const float* __restrict__ cb,
    const unsigned short* __restrict__ Bhi, const unsigned short* __restrict__ Blo,
    const float* __restrict__ dtW, const float* __restrict__ dtbias,
    const float* __restrict__ A_log,
    float* __restrict__ dbl,
    float* __restrict__ S, float* __restrict__ sdt)
{
    __shared__ unsigned short sAh[16*520], sAl[16*520];
    __shared__ float sP[6][16][20];
    __shared__ float sD[16*52];

    int tid = threadIdx.x;
    int wave = tid >> 6, lane = tid & 63;
    int lr = lane & 15, kq = (lane>>4)*8, quad4 = (lane>>4)*4;
    int m0 = blockIdx.x * LCH;
    int d  = tid;
    int nt = wave >> 1, kh = wave & 1;

    float xv[19];
    {
        int rbase = m0 - 3;
        bool mask0 = ((m0 & (T_-1)) == 0);
#pragma unroll
        for(int j=0;j<19;j++)
            xv[j] = (mask0 && j<3) ? 0.f : xz[(size_t)(rbase+j)*DX + d];
    }
    float4 w4 = *(const float4*)(cw + d*4);
    float bias = cb[d];
    float vh[16];
#pragma unroll
    for(int t=0;t<16;t++){
        float a = bias + w4.x*xv[t] + w4.y*xv[t+1] + w4.z*xv[t+2] + w4.w*xv[t+3];
        float v = a * sigmoidf_(a);
        vh[t] = v;
        unsigned short hh = f2bf(v);
        sAh[t*520 + d] = hh;
        sAl[t*520 + d] = f2bf(v - bf2f(hh));
    }
    __syncthreads();

    if(wave < 6){
        const unsigned short* bhp = Bhi + (size_t)(nt*16 + lr)*DI + kh*256 + kq;
        const unsigned short* blp = Blo + (size_t)(nt*16 + lr)*DI + kh*256 + kq;
        f32x4 acc = {0.f,0.f,0.f,0.f};
#pragma unroll 4
        for(int ks=0;ks<8;ks++){
            int ao = lr*520 + kh*256 + ks*32 + kq;
            bf16x8 ah = *(const bf16x8*)(&sAh[ao]);
            bf16x8 al = *(const bf16x8*)(&sAl[ao]);
            bf16x8 bh = *(const bf16x8*)(bhp + ks*32);
            bf16x8 bl = *(const bf16x8*)(blp + ks*32);
            acc = __builtin_amdgcn_mfma_f32_16x16x32_bf16(ah, bh, acc, 0,0,0);
            acc = __builtin_amdgcn_mfma_f32_16x16x32_bf16(ah, bl, acc, 0,0,0);
            acc = __builtin_amdgcn_mfma_f32_16x16x32_bf16(al, bh, acc, 0,0,0);
        }
#pragma unroll
        for(int r=0;r<4;r++) sP[wave][quad4+r][lr] = acc[r];
    }
    __syncthreads();

    for(int i=tid;i<768;i+=512){
        int t = i/48, n = i - t*48;
        int nt2 = n >> 4, nn = n & 15;
        float v = sP[nt2*2][t][nn] + sP[nt2*2+1][t][nn];
        dbl[(size_t)(m0+t)*48 + n] = v;
        sD[t*52 + n] = v;
    }
    __syncthreads();

    // scan parameters loaded late (smaller live range through phases A/B)
    float a_[16]; ld16(A_log + (size_t)d*16, a_);
#pragma unroll
    for(int n=0;n<16;n++) a_[n] = -__expf(a_[n]);
    float wr_[16]; ld16(dtW + (size_t)d*16, wr_);
    float bsv = dtbias[d];
    int b = m0 >> 11;
    int c = (m0 & (T_-1)) >> 4;
    float st_[16];
#pragma unroll
    for(int n=0;n<16;n++) st_[n] = 0.f;
    float sd = 0.f;
#pragma unroll 4
    for(int t=0;t<16;t++){
        float dl[16]; ld16(&sD[t*52], dl);
        float bv[16]; ld16(&sD[t*52 + 16], bv);
        float pre = bsv;
#pragma unroll
        for(int r=0;r<16;r++) pre += dl[r]*wr_[r];
        float dtv = softplusf_(pre);
        float dx = dtv*vh[t];
        sd += dtv;
#pragma unroll
        for(int n=0;n<16;n++) st_[n] = __expf(dtv*a_[n])*st_[n] + dx*bv[n];
    }
    st16(S + (((size_t)b*NC_ + c)*DI + d)*16, st_);
    sdt[((size_t)b*NC_ + c)*DI + d] = sd;
}

// ---- pass 2: inter-chunk scan (8-way unrolled; 128-thread blocks so all CUs occupied) ----
__global__ void k_scan2(const float* __restrict__ S, const float* __restrict__ sdt,
                        const float* __restrict__ A_log, float* __restrict__ Hinit){
    int g = blockIdx.x*128 + threadIdx.x;
    int b = g >> 13;
    int dn = g & 8191;
    int d = dn >> 4;
    float a = -__expf(A_log[dn]);
    float H = 0.f;
    for(int c0=0;c0<NC_;c0+=8){
        float sv[8], gv[8];
#pragma unroll
        for(int j=0;j<8;j++){
            sv[j] = S[((size_t)(b*NC_ + c0 + j))*8192 + dn];
            gv[j] = sdt[(size_t)(b*NC_ + c0 + j)*DI + d];
        }
#pragma unroll
        for(int j=0;j<8;j++){
            size_t o = ((size_t)(b*NC_ + c0 + j))*8192 + dn;
            Hinit[o] = H;
            H = __expf(gv[j]*a)*H + sv[j];
        }
    }
}

// ---- scan pass-3 (layers 0..2): replay (conv+dt recomputed) + gate, packed Y ----
__global__ void __launch_bounds__(256) k_scan3(
    const float* __restrict__ dbl, const float* __restrict__ xz,
    const float* __restrict__ cvw, const float* __restrict__ cvb,
    const float* __restrict__ A_log, const float* __restrict__ Dpar,
    const float* __restrict__ dtW, const float* __restrict__ dtbias,
    const float* __restrict__ Hinit, unsigned* __restrict__ Y)
{
    __shared__ float sbc[16*52];
    int tid = threadIdx.x;
    int c = blockIdx.y, b = blockIdx.z;
    int m0 = b*T_ + c*LCH;
    if(tid < 192){
        int t = tid/12, s = tid - t*12;
        *(float4*)(&sbc[t*52 + s*4]) = *(const float4*)(dbl + (size_t)(m0+t)*48 + s*4);
    }
    __syncthreads();
    int d = blockIdx.x*256 + tid;
    float xv[19];
    {
        int rbase = m0 - 3;
        bool mask0 = (c == 0);
#pragma unroll
        for(int j=0;j<19;j++)
            xv[j] = (mask0 && j<3) ? 0.f : xz[(size_t)(rbase+j)*DX + d];
    }
    float zvp[16];
#pragma unroll
    for(int t=0;t<16;t++) zvp[t] = xz[(size_t)(m0+t)*DX + DI + d];
    float4 w4 = *(const float4*)(cvw + d*4);
    float bias = cvb[d];
    float xhp[16];
#pragma unroll
    for(int t=0;t<16;t++){
        float a = bias + w4.x*xv[t] + w4.y*xv[t+1] + w4.z*xv[t+2] + w4.w*xv[t+3];
        xhp[t] = a * sigmoidf_(a);
    }
    float a_[16]; ld16(A_log + (size_t)d*16, a_);
#pragma unroll
    for(int n=0;n<16;n++) a_[n] = -__expf(a_[n]);
    float wr_[16]; ld16(dtW + (size_t)d*16, wr_);
    float bsv = dtbias[d];
    float st_[16]; ld16(Hinit + (((size_t)b*NC_ + c)*DI + d)*16, st_);
    float Dp = Dpar[d];
#pragma unroll 2
    for(int t=0;t<LCH;t++){
        int bt = m0 + t;
        float dl[16]; ld16(&sbc[t*52], dl);
        float bv[16]; ld16(&sbc[t*52 + 16], bv);
        float cv[16]; ld16(&sbc[t*52 + 32], cv);
        float pre = bsv;
#pragma unroll
        for(int r=0;r<16;r++) pre += dl[r]*wr_[r];
        float dtv = softplusf_(pre);
        float xhv = xhp[t];
        float dx = dtv*xhv;
        float y = 0.f;
#pragma unroll
        for(int n=0;n<16;n++){
            st_[n] = __expf(dtv*a_[n])*st_[n] + dx*bv[n];
            y += st_[n]*cv[n];
        }
        float zv = zvp[t];
        y += Dp*xhv;
        y = y * zv * sigmoidf_(zv);
        unsigned short hh = f2bf(y);
        unsigned short ll = f2bf(y - bf2f(hh));
        Y[(size_t)bt*DI + d] = (unsigned)hh | ((unsigned)ll << 16);
    }
}

// ---- scan pass-3 for LAST layer: fused with final output dot (writes d_out) ----
__global__ void __launch_bounds__(512) k_scan3o(
    const float* __restrict__ dbl, const float* __restrict__ xz,
    const float* __restrict__ cvw, const float* __restrict__ cvb,
    const float* __restrict__ A_log, const float* __restrict__ Dpar,
    const float* __restrict__ dtW, const float* __restrict__ dtbias,
    const float* __restrict__ Hinit, const float* __restrict__ cwc,
    float* __restrict__ out)
{
    __shared__ float sbc[16*52];
    __shared__ float sW[8][16];
    int tid = threadIdx.x;
    int c = blockIdx.x, b = blockIdx.y;
    int m0 = b*T_ + c*LCH;
    if(tid < 192){
        int t = tid/12, s = tid - t*12;
        *(float4*)(&sbc[t*52 + s*4]) = *(const float4*)(dbl + (size_t)(m0+t)*48 + s*4);
    }
    __syncthreads();
    int d = tid;
    int wave = tid >> 6, lane = tid & 63;
    float xv[19];
    {
        int rbase = m0 - 3;
        bool mask0 = (c == 0);
#pragma unroll
        for(int j=0;j<19;j++)
            xv[j] = (mask0 && j<3) ? 0.f : xz[(size_t)(rbase+j)*DX + d];
    }
    float zvp[16];
#pragma unroll
    for(int t=0;t<16;t++) zvp[t] = xz[(size_t)(m0+t)*DX + DI + d];
    float4 w4 = *(const float4*)(cvw + d*4);
    float bias = cvb[d];
    float xhp[16];
#pragma unroll
    for(int t=0;t<16;t++){
        float a = bias + w4.x*xv[t] + w4.y*xv[t+1] + w4.z*xv[t+2] + w4.w*xv[t+3];
        xhp[t] = a * sigmoidf_(a);
    }
    float a_[16]; ld16(A_log + (size_t)d*16, a_);
#pragma unroll
    for(int n=0;n<16;n++) a_[n] = -__expf(a_[n]);
    float wr_[16]; ld16(dtW + (size_t)d*16, wr_);
    float bsv = dtbias[d];
    float st_[16]; ld16(Hinit + (((size_t)b*NC_ + c)*DI + d)*16, st_);
    float Dp = Dpar[d];
    float cwv = cwc[d];
#pragma unroll 2
    for(int t=0;t<LCH;t++){
        float dl[16]; ld16(&sbc[t*52], dl);
        float bv[16]; ld16(&sbc[t*52 + 16], bv);
        float cv[16]; ld16(&sbc[t*52 + 32], cv);
        float pre = bsv;
#pragma unroll
        for(int r=0;r<16;r++) pre += dl[r]*wr_[r];
        float dtv = softplusf_(pre);
        float xhv = xhp[t];
        float dx = dtv*xhv;
        float y = 0.f;
#pragma unroll
        for(int n=0;n<16;n++){
            st_[n] = __expf(dtv*a_[n])*st_[n] + dx*bv[n];
            y += st_[n]*cv[n];
        }
        float zv = zvp[t];
        y += Dp*xhv;
        y = y * zv * sigmoidf_(zv);
        float s = y * cwv;
#pragma unroll
        for(int m=1;m<64;m<<=1) s += __shfl_xor(s,m);
        if(lane==0) sW[wave][t] = s;
    }
    __syncthreads();
    if(tid < 16){
        float s = 0.f;
#pragma unroll
        for(int w=0;w<8;w++) s += sW[w][tid];
        out[m0 + tid] = s;
    }
}

extern "C" void kernel_launch(void* const* d_in, const int* in_sizes, int n_in,
                              void* d_out, int out_size, void* d_ws, size_t ws_size,
                              hipStream_t stream){
    const float* x_src    = (const float*)d_in[0];
    const float* in_W     = (const float*)d_in[2];
    const float* norm_w   = (const float*)d_in[3];
    const float* norm_b   = (const float*)d_in[4];
    const float* inproj_W = (const float*)d_in[5];
    const float* conv_w   = (const float*)d_in[6];
    const float* conv_b   = (const float*)d_in[7];
    const float* xproj_W  = (const float*)d_in[8];
    const float* dtproj_W = (const float*)d_in[9];
    const float* dtproj_b = (const float*)d_in[10];
    const float* A_log    = (const float*)d_in[11];
    const float* D_param  = (const float*)d_in[12];
    const float* outproj_W= (const float*)d_in[13];
    const float* out_W    = (const float*)d_in[14];

    float* ws  = (float*)d_ws;
    float* res  = ws;                        // BT*DM
    float* xz   = res  + (size_t)BT_*DM;     // BT*DX
    float* dbl  = xz   + (size_t)BT_*DX;     // BT*48
    float* sdtb = dbl  + (size_t)BT_*48;     // B*NC*DI
    float* Sbuf = sdtb + (size_t)B_*NC_*DI;  // B*NC*DI*16
    float* Hbuf = Sbuf + (size_t)B_*NC_*DI*DS_;
    unsigned short* us = (unsigned short*)(Hbuf + (size_t)B_*NC_*DI*DS_);
    unsigned short* WhiIn  = us;                                  // NL*DX*DM
    unsigned short* WloIn  = WhiIn  + (size_t)NL*DX*DM;
    unsigned short* WhiOut = WloIn  + (size_t)NL*DX*DM;           // NL*DM*DI
    unsigned short* WloOut = WhiOut + (size_t)NL*DM*DI;
    unsigned short* WhiXp  = WloOut + (size_t)NL*DM*DI;           // NL*NO*DI
    unsigned short* WloXp  = WhiXp  + (size_t)NL*NO_*DI;
    unsigned short* hnhi   = WloXp  + (size_t)NL*NO_*DI;          // BT*DM
    unsigned short* hnlo   = hnhi   + (size_t)BT_*DM;
    unsigned*       ybuf   = (unsigned*)(hnlo + (size_t)BT_*DM);  // BT*DI
    float*          cwb    = (float*)(ybuf + (size_t)BT_*DI);     // DI
    unsigned*       cntb   = (unsigned*)(cwb + DI);               // 3*128

    k_init<<<NCVT + NINL, 256, 0, stream>>>(
        inproj_W,  WhiIn,  WloIn,
        outproj_W, WhiOut, WloOut,
        xproj_W,   WhiXp,  WloXp,
        outproj_W + (size_t)3*DM*DI, out_W, cwb,
        x_src, in_W, res, hnhi, hnlo, norm_w, norm_b, cntb);
    for(int i=0;i<NL;i++){
        k_gemm_bf3<64,128><<<dim3(DX/128, BT_/64), 256, 0, stream>>>(
            hnhi, hnlo, WhiIn + (size_t)i*DX*DM, WloIn + (size_t)i*DX*DM, xz, BT_, DX, DM);
        k_convxp2<<<BT_/LCH, 512, 0, stream>>>(xz, conv_w + i*DI*4, conv_b + i*DI,
            WhiXp + (size_t)i*NO_*DI, WloXp + (size_t)i*NO_*DI,
            dtproj_W + (size_t)i*DI*DR_, dtproj_b + i*DI,
            A_log + (size_t)i*DI*DS_, dbl, Sbuf, sdtb);
        k_scan2<<<B_*DI*DS_/128, 128, 0, stream>>>(Sbuf, sdtb, A_log + (size_t)i*DI*DS_, Hbuf);
        if(i < NL-1){
            k_scan3<<<dim3(2, NC_, B_), 256, 0, stream>>>(dbl, xz,
                conv_w + i*DI*4, conv_b + i*DI,
                A_log + (size_t)i*DI*DS_, D_param + i*DI,
                dtproj_W + (size_t)i*DI*DR_, dtproj_b + i*DI, Hbuf, ybuf);
            k_gemm_pk_res<<<dim3(DM/64, BT_/64), 256, 0, stream>>>(
                ybuf, WhiOut + (size_t)i*DM*DI, WloOut + (size_t)i*DM*DI, res,
                hnhi, hnlo, norm_w + (i+1)*DM, norm_b + (i+1)*DM, cntb + i*128);
        } else {
            k_scan3o<<<dim3(NC_, B_), 512, 0, stream>>>(dbl, xz,
                conv_w + i*DI*4, conv_b + i*DI,
                A_log + (size_t)i*DI*DS_, D_param + i*DI,
                dtproj_W + (size_t)i*DI*DR_, dtproj_b + i*DI, Hbuf, cwb,
                (float*)d_out);
        }
    }
}

// Round 15
// 528.480 us; speedup vs baseline: 1.5143x; 1.5143x over previous
//
#include <hip/hip_runtime.h>

#define B_   4
#define T_   2048
#define BT_  8192
#define INL  15
#define DM   256
#define DI   512
#define DX   1024
#define DS_  16
#define DR_  16
#define NO_  48
#define NL   4
#define NC_  128
#define LCH  16

// k_init block partition: cvt blocks then inln blocks
#define N0C  (NL*DX*DM/4)
#define N1C  (NL*DM*DI/4)
#define N2C  (NL*NO_*DI/4)
#define NCVT ((N0C + N1C + N2C + DI + 255)/256)
#define NINL (BT_/4)

typedef short bf16x8 __attribute__((ext_vector_type(8)));
typedef float f32x4  __attribute__((ext_vector_type(4)));

__device__ __forceinline__ float sigmoidf_(float x){
    return __builtin_amdgcn_rcpf(1.f + __expf(-x));
}
__device__ __forceinline__ float softplusf_(float x){
    return fmaxf(x, 0.f) + __logf(1.f + __expf(-fabsf(x)));
}

__device__ __forceinline__ unsigned short f2bf(float x){
    union { float f; unsigned u; } v; v.f = x;
    unsigned r = (v.u + 0x7FFFu + ((v.u >> 16) & 1u)) >> 16;
    return (unsigned short)r;
}
__device__ __forceinline__ float bf2f(unsigned short h){
    union { unsigned u; float f; } v; v.u = ((unsigned)h) << 16;
    return v.f;
}

__device__ __forceinline__ void ld16(const float* __restrict__ p, float* v){
    const float4* q = (const float4*)p;
    float4 x0=q[0],x1=q[1],x2=q[2],x3=q[3];
    v[0]=x0.x; v[1]=x0.y; v[2]=x0.z; v[3]=x0.w;
    v[4]=x1.x; v[5]=x1.y; v[6]=x1.z; v[7]=x1.w;
    v[8]=x2.x; v[9]=x2.y; v[10]=x2.z; v[11]=x2.w;
    v[12]=x3.x; v[13]=x3.y; v[14]=x3.z; v[15]=x3.w;
}
__device__ __forceinline__ void st16(float* __restrict__ p, const float* v){
    float4* q = (float4*)p;
    q[0] = make_float4(v[0],v[1],v[2],v[3]);
    q[1] = make_float4(v[4],v[5],v[6],v[7]);
    q[2] = make_float4(v[8],v[9],v[10],v[11]);
    q[3] = make_float4(v[12],v[13],v[14],v[15]);
}

// ---- merged prologue: weight cvt (+ combined last-layer weight) | input GEMM + LN ----
__global__ void k_init(const float* __restrict__ W0, unsigned short* __restrict__ h0,
                       unsigned short* __restrict__ l0,
                       const float* __restrict__ W1, unsigned short* __restrict__ h1,
                       unsigned short* __restrict__ l1,
                       const float* __restrict__ W2, unsigned short* __restrict__ h2,
                       unsigned short* __restrict__ l2,
                       const float* __restrict__ opW3, const float* __restrict__ outW,
                       float* __restrict__ cwc,
                       const float* __restrict__ x, const float* __restrict__ W,
                       float* __restrict__ res,
                       unsigned short* __restrict__ hnhi, unsigned short* __restrict__ hnlo,
                       const float* __restrict__ w, const float* __restrict__ b){
    int bid = blockIdx.x;
    if(bid < NCVT){
        int g = bid*256 + threadIdx.x;
        const float* Wp; unsigned short *hi, *lo; int idx;
        if(g < N0C){ Wp = W0; hi = h0; lo = l0; idx = g; }
        else if(g < N0C+N1C){ Wp = W1; hi = h1; lo = l1; idx = g - N0C; }
        else if(g < N0C+N1C+N2C){ Wp = W2; hi = h2; lo = l2; idx = g - N0C - N1C; }
        else {
            int k = g - (N0C+N1C+N2C);
            if(k < DI){
                float s = 0.f;
#pragma unroll 8
                for(int m=0;m<DM;m++) s += outW[m]*opW3[(size_t)m*DI + k];
                cwc[k] = s;
            }
            return;
        }
        float4 v = ((const float4*)Wp)[idx];
        ushort4 h, l;
        h.x = f2bf(v.x); l.x = f2bf(v.x - bf2f(h.x));
        h.y = f2bf(v.y); l.y = f2bf(v.y - bf2f(h.y));
        h.z = f2bf(v.z); l.z = f2bf(v.z - bf2f(h.z));
        h.w = f2bf(v.w); l.w = f2bf(v.w - bf2f(h.w));
        ((ushort4*)hi)[idx] = h;
        ((ushort4*)lo)[idx] = l;
        return;
    }
    // inln part
    int wv = threadIdx.x >> 6, lane = threadIdx.x & 63;
    int bt = (bid - NCVT)*4 + wv;
    const float* xr = x + bt*INL;
    float xl[INL];
#pragma unroll
    for(int k=0;k<INL;k++) xl[k] = xr[k];
    float4 v;
    float* vv = (float*)&v;
#pragma unroll
    for(int j=0;j<4;j++){
        int m = lane*4 + j;
        const float* wr = W + m*INL;
        float acc = 0.f;
#pragma unroll
        for(int k=0;k<INL;k++) acc += xl[k]*wr[k];
        vv[j] = acc;
    }
    ((float4*)(res + (size_t)bt*DM))[lane] = v;
    float s  = v.x+v.y+v.z+v.w;
    float ss = v.x*v.x+v.y*v.y+v.z*v.z+v.w*v.w;
#pragma unroll
    for(int m=1;m<64;m<<=1){ s += __shfl_xor(s,m); ss += __shfl_xor(ss,m); }
    float mean = s*(1.f/DM);
    float var  = ss*(1.f/DM) - mean*mean;
    float inv  = rsqrtf(var + 1e-5f);
    float4 wt = ((const float4*)w)[lane];
    float4 bs = ((const float4*)b)[lane];
    float4 o;
    o.x = (v.x-mean)*inv*wt.x + bs.x;
    o.y = (v.y-mean)*inv*wt.y + bs.y;
    o.z = (v.z-mean)*inv*wt.z + bs.z;
    o.w = (v.w-mean)*inv*wt.w + bs.w;
    ushort4 hh, ll;
    hh.x = f2bf(o.x); ll.x = f2bf(o.x - bf2f(hh.x));
    hh.y = f2bf(o.y); ll.y = f2bf(o.y - bf2f(hh.y));
    hh.z = f2bf(o.z); ll.z = f2bf(o.z - bf2f(hh.z));
    hh.w = f2bf(o.w); ll.w = f2bf(o.w - bf2f(hh.w));
    ((ushort4*)(hnhi + (size_t)bt*DM))[lane] = hh;
    ((ushort4*)(hnlo + (size_t)bt*DM))[lane] = ll;
}

// LN-only: hn = LN(res)*w+b -> bf16 hi/lo  (res already holds the running residual)
__global__ void k_resln(const float* __restrict__ res,
                        unsigned short* __restrict__ hnhi, unsigned short* __restrict__ hnlo,
                        const float* __restrict__ w, const float* __restrict__ b){
    int wv = threadIdx.x >> 6, lane = threadIdx.x & 63;
    int bt = blockIdx.x*4 + wv;
    float4 v = ((const float4*)(res + (size_t)bt*DM))[lane];
    float s  = v.x+v.y+v.z+v.w;
    float ss = v.x*v.x+v.y*v.y+v.z*v.z+v.w*v.w;
#pragma unroll
    for(int m=1;m<64;m<<=1){ s += __shfl_xor(s,m); ss += __shfl_xor(ss,m); }
    float mean = s*(1.f/DM);
    float var  = ss*(1.f/DM) - mean*mean;
    float inv  = rsqrtf(var + 1e-5f);
    float4 wt = ((const float4*)w)[lane];
    float4 bs = ((const float4*)b)[lane];
    float4 o;
    o.x = (v.x-mean)*inv*wt.x + bs.x;
    o.y = (v.y-mean)*inv*wt.y + bs.y;
    o.z = (v.z-mean)*inv*wt.z + bs.z;
    o.w = (v.w-mean)*inv*wt.w + bs.w;
    ushort4 hh, ll;
    hh.x = f2bf(o.x); ll.x = f2bf(o.x - bf2f(hh.x));
    hh.y = f2bf(o.y); ll.y = f2bf(o.y - bf2f(hh.y));
    hh.z = f2bf(o.z); ll.z = f2bf(o.z - bf2f(hh.z));
    hh.w = f2bf(o.w); ll.w = f2bf(o.w - bf2f(hh.w));
    ((ushort4*)(hnhi + (size_t)bt*DM))[lane] = hh;
    ((ushort4*)(hnlo + (size_t)bt*DM))[lane] = ll;
}

// C[M][N] = A[M][K] @ Bw[N][K]^T via bf16 MFMA, hi/lo 3-term split (inproj)
template<int BM,int BN>
__global__ void __launch_bounds__(256) k_gemm_bf3(
    const unsigned short* __restrict__ Ahi, const unsigned short* __restrict__ Alo,
    const unsigned short* __restrict__ Bhi, const unsigned short* __restrict__ Blo,
    float* __restrict__ C, int M, int N, int K)
{
    constexpr int LDP = 40;
    constexpr int WM = BM/2, WN = BN/2;
    constexpr int MI_ = WM/16, NI_ = WN/16;
    __shared__ unsigned short sAh[BM*LDP], sAl[BM*LDP], sBh[BN*LDP], sBl[BN*LDP];
    int tid  = threadIdx.x;
    int wave = tid >> 6, lane = tid & 63;
    int wm0  = (wave >> 1) * WM, wn0 = (wave & 1) * WN;
    int m0   = blockIdx.y * BM, n0 = blockIdx.x * BN;
    int lr   = lane & 15;
    int kq   = (lane >> 4) * 8;
    int quad4 = (lane >> 4) * 4;

    f32x4 acc[MI_][NI_];
#pragma unroll
    for(int i=0;i<MI_;i++)
#pragma unroll
        for(int j=0;j<NI_;j++) acc[i][j] = (f32x4){0.f,0.f,0.f,0.f};

    for(int k0=0;k0<K;k0+=32){
#pragma unroll
        for(int i=tid;i<BM*4;i+=256){
            int r = i>>2, cg2 = (i&3)*8;
            size_t go = (size_t)(m0+r)*K + k0 + cg2;
            *(float4*)(&sAh[r*LDP + cg2]) = *(const float4*)(Ahi + go);
            *(float4*)(&sAl[r*LDP + cg2]) = *(const float4*)(Alo + go);
        }
#pragma unroll
        for(int i=tid;i<BN*4;i+=256){
            int r = i>>2, cg2 = (i&3)*8;
            size_t go = (size_t)(n0+r)*K + k0 + cg2;
            *(float4*)(&sBh[r*LDP + cg2]) = *(const float4*)(Bhi + go);
            *(float4*)(&sBl[r*LDP + cg2]) = *(const float4*)(Blo + go);
        }
        __syncthreads();
        bf16x8 ah[MI_], al[MI_], bh[NI_], bl[NI_];
#pragma unroll
        for(int mi=0;mi<MI_;mi++){
            int ro = (wm0 + mi*16 + lr)*LDP + kq;
            ah[mi] = *(const bf16x8*)(&sAh[ro]);
            al[mi] = *(const bf16x8*)(&sAl[ro]);
        }
#pragma unroll
        for(int ni=0;ni<NI_;ni++){
            int ro = (wn0 + ni*16 + lr)*LDP + kq;
            bh[ni] = *(const bf16x8*)(&sBh[ro]);
            bl[ni] = *(const bf16x8*)(&sBl[ro]);
        }
#pragma unroll
        for(int mi=0;mi<MI_;mi++)
#pragma unroll
            for(int ni=0;ni<NI_;ni++){
                acc[mi][ni] = __builtin_amdgcn_mfma_f32_16x16x32_bf16(ah[mi], bh[ni], acc[mi][ni], 0,0,0);
                acc[mi][ni] = __builtin_amdgcn_mfma_f32_16x16x32_bf16(ah[mi], bl[ni], acc[mi][ni], 0,0,0);
                acc[mi][ni] = __builtin_amdgcn_mfma_f32_16x16x32_bf16(al[mi], bh[ni], acc[mi][ni], 0,0,0);
            }
        __syncthreads();
    }
#pragma unroll
    for(int mi=0;mi<MI_;mi++)
#pragma unroll
        for(int ni=0;ni<NI_;ni++){
            int col = n0 + wn0 + ni*16 + lr;
#pragma unroll
            for(int r=0;r<4;r++){
                int row = m0 + wm0 + mi*16 + quad4 + r;
                C[(size_t)row*N + col] = acc[mi][ni][r];
            }
        }
}

// ---- outproj (layers 0..2): GEMM on packed Y, epilogue res += C (64x64 tile) ----
__global__ void __launch_bounds__(256) k_gemm_pk_res(
    const unsigned* __restrict__ Apk,
    const unsigned short* __restrict__ Bhi, const unsigned short* __restrict__ Blo,
    float* __restrict__ res)
{
    constexpr int BM = 64, BN = 64, K = 512, LDP = 40;
    __shared__ unsigned short sAh[BM*LDP], sAl[BM*LDP], sBh[BN*LDP], sBl[BN*LDP];
    int tid  = threadIdx.x;
    int wave = tid >> 6, lane = tid & 63;
    int wm0  = (wave >> 1) * 32, wn0 = (wave & 1) * 32;
    int m0   = blockIdx.y * BM, n0 = blockIdx.x * BN;
    int lr   = lane & 15;
    int kq   = (lane >> 4) * 8;
    int quad4 = (lane >> 4) * 4;

    f32x4 acc[2][2];
#pragma unroll
    for(int i=0;i<2;i++)
#pragma unroll
        for(int j=0;j<2;j++) acc[i][j] = (f32x4){0.f,0.f,0.f,0.f};

    for(int k0=0;k0<K;k0+=32){
        if(tid < BM*2){
            int r = tid>>1, hf = (tid&1)*16;
            const uint4* yp = (const uint4*)(Apk + (size_t)(m0+r)*K + k0 + hf);
#pragma unroll
            for(int q=0;q<4;q++){
                uint4 p = yp[q];
                ushort4 H, L;
                H.x=(unsigned short)p.x;  L.x=(unsigned short)(p.x>>16);
                H.y=(unsigned short)p.y;  L.y=(unsigned short)(p.y>>16);
                H.z=(unsigned short)p.z;  L.z=(unsigned short)(p.z>>16);
                H.w=(unsigned short)p.w;  L.w=(unsigned short)(p.w>>16);
                *(ushort4*)(&sAh[r*LDP + hf + q*4]) = H;
                *(ushort4*)(&sAl[r*LDP + hf + q*4]) = L;
            }
        }
        {
            int r = tid>>2, cg2 = (tid&3)*8;
            size_t go = (size_t)(n0+r)*K + k0 + cg2;
            *(float4*)(&sBh[r*LDP + cg2]) = *(const float4*)(Bhi + go);
            *(float4*)(&sBl[r*LDP + cg2]) = *(const float4*)(Blo + go);
        }
        __syncthreads();
        bf16x8 ah[2], al[2], bh[2], bl[2];
#pragma unroll
        for(int mi=0;mi<2;mi++){
            int ro = (wm0 + mi*16 + lr)*LDP + kq;
            ah[mi] = *(const bf16x8*)(&sAh[ro]);
            al[mi] = *(const bf16x8*)(&sAl[ro]);
        }
#pragma unroll
        for(int ni=0;ni<2;ni++){
            int ro = (wn0 + ni*16 + lr)*LDP + kq;
            bh[ni] = *(const bf16x8*)(&sBh[ro]);
            bl[ni] = *(const bf16x8*)(&sBl[ro]);
        }
#pragma unroll
        for(int mi=0;mi<2;mi++)
#pragma unroll
            for(int ni=0;ni<2;ni++){
                acc[mi][ni] = __builtin_amdgcn_mfma_f32_16x16x32_bf16(ah[mi], bh[ni], acc[mi][ni], 0,0,0);
                acc[mi][ni] = __builtin_amdgcn_mfma_f32_16x16x32_bf16(ah[mi], bl[ni], acc[mi][ni], 0,0,0);
                acc[mi][ni] = __builtin_amdgcn_mfma_f32_16x16x32_bf16(al[mi], bh[ni], acc[mi][ni], 0,0,0);
            }
        __syncthreads();
    }
    // epilogue: res += C (each (row,col) owned by exactly one thread)
#pragma unroll
    for(int mi=0;mi<2;mi++)
#pragma unroll
        for(int ni=0;ni<2;ni++){
            int col = n0 + wn0 + ni*16 + lr;
#pragma unroll
            for(int r=0;r<4;r++){
                int row = m0 + wm0 + mi*16 + quad4 + r;
                size_t o = (size_t)row*DM + col;
                res[o] += acc[mi][ni][r];
            }
        }
}

// ---- conv+SiLU | xproj MFMA (B streamed from L2) | lean fused scan pass-1 ----
__global__ void __launch_bounds__(512) k_convxp2(
    const float* __restrict__ xz, const float* __restrict__ cw, const float* __restrict__ cb,
    const unsigned short* __restrict__ Bhi, const unsigned short* __restrict__ Blo,
    const float* __restrict__ dtW, const float* __restrict__ dtbias,
    const float* __restrict__ A_log,
    float* __restrict__ dbl,
    float* __restrict__ S, float* __restrict__ sdt)
{
    __shared__ unsigned short sAh[16*520], sAl[16*520];
    __shared__ float sP[6][16][20];
    __shared__ float sD[16*52];

    int tid = threadIdx.x;
    int wave = tid >> 6, lane = tid & 63;
    int lr = lane & 15, kq = (lane>>4)*8, quad4 = (lane>>4)*4;
    int m0 = blockIdx.x * LCH;
    int d  = tid;
    int nt = wave >> 1, kh = wave & 1;

    float xv[19];
    {
        int rbase = m0 - 3;
        bool mask0 = ((m0 & (T_-1)) == 0);
#pragma unroll
        for(int j=0;j<19;j++)
            xv[j] = (mask0 && j<3) ? 0.f : xz[(size_t)(rbase+j)*DX + d];
    }
    float4 w4 = *(const float4*)(cw + d*4);
    float bias = cb[d];
    float vh[16];
#pragma unroll
    for(int t=0;t<16;t++){
        float a = bias + w4.x*xv[t] + w4.y*xv[t+1] + w4.z*xv[t+2] + w4.w*xv[t+3];
        float v = a * sigmoidf_(a);
        vh[t] = v;
        unsigned short hh = f2bf(v);
        sAh[t*520 + d] = hh;
        sAl[t*520 + d] = f2bf(v - bf2f(hh));
    }
    __syncthreads();

    if(wave < 6){
        const unsigned short* bhp = Bhi + (size_t)(nt*16 + lr)*DI + kh*256 + kq;
        const unsigned short* blp = Blo + (size_t)(nt*16 + lr)*DI + kh*256 + kq;
        f32x4 acc = {0.f,0.f,0.f,0.f};
#pragma unroll 4
        for(int ks=0;ks<8;ks++){
            int ao = lr*520 + kh*256 + ks*32 + kq;
            bf16x8 ah = *(const bf16x8*)(&sAh[ao]);
            bf16x8 al = *(const bf16x8*)(&sAl[ao]);
            bf16x8 bh = *(const bf16x8*)(bhp + ks*32);
            bf16x8 bl = *(const bf16x8*)(blp + ks*32);
            acc = __builtin_amdgcn_mfma_f32_16x16x32_bf16(ah, bh, acc, 0,0,0);
            acc = __builtin_amdgcn_mfma_f32_16x16x32_bf16(ah, bl, acc, 0,0,0);
            acc = __builtin_amdgcn_mfma_f32_16x16x32_bf16(al, bh, acc, 0,0,0);
        }
#pragma unroll
        for(int r=0;r<4;r++) sP[wave][quad4+r][lr] = acc[r];
    }
    __syncthreads();

    for(int i=tid;i<768;i+=512){
        int t = i/48, n = i - t*48;
        int nt2 = n >> 4, nn = n & 15;
        float v = sP[nt2*2][t][nn] + sP[nt2*2+1][t][nn];
        dbl[(size_t)(m0+t)*48 + n] = v;
        sD[t*52 + n] = v;
    }
    __syncthreads();

    // scan parameters loaded late (smaller live range through phases A/B)
    float a_[16]; ld16(A_log + (size_t)d*16, a_);
#pragma unroll
    for(int n=0;n<16;n++) a_[n] = -__expf(a_[n]);
    float wr_[16]; ld16(dtW + (size_t)d*16, wr_);
    float bsv = dtbias[d];
    int b = m0 >> 11;
    int c = (m0 & (T_-1)) >> 4;
    float st_[16];
#pragma unroll
    for(int n=0;n<16;n++) st_[n] = 0.f;
    float sd = 0.f;
#pragma unroll 4
    for(int t=0;t<16;t++){
        float dl[16]; ld16(&sD[t*52], dl);
        float bv[16]; ld16(&sD[t*52 + 16], bv);
        float pre = bsv;
#pragma unroll
        for(int r=0;r<16;r++) pre += dl[r]*wr_[r];
        float dtv = softplusf_(pre);
        float dx = dtv*vh[t];
        sd += dtv;
#pragma unroll
        for(int n=0;n<16;n++) st_[n] = __expf(dtv*a_[n])*st_[n] + dx*bv[n];
    }
    st16(S + (((size_t)b*NC_ + c)*DI + d)*16, st_);
    sdt[((size_t)b*NC_ + c)*DI + d] = sd;
}

// ---- pass 2: inter-chunk scan (8-way unrolled; 128-thread blocks so all CUs occupied) ----
__global__ void k_scan2(const float* __restrict__ S, const float* __restrict__ sdt,
                        const float* __restrict__ A_log, float* __restrict__ Hinit){
    int g = blockIdx.x*128 + threadIdx.x;
    int b = g >> 13;
    int dn = g & 8191;
    int d = dn >> 4;
    float a = -__expf(A_log[dn]);
    float H = 0.f;
    for(int c0=0;c0<NC_;c0+=8){
        float sv[8], gv[8];
#pragma unroll
        for(int j=0;j<8;j++){
            sv[j] = S[((size_t)(b*NC_ + c0 + j))*8192 + dn];
            gv[j] = sdt[(size_t)(b*NC_ + c0 + j)*DI + d];
        }
#pragma unroll
        for(int j=0;j<8;j++){
            size_t o = ((size_t)(b*NC_ + c0 + j))*8192 + dn;
            Hinit[o] = H;
            H = __expf(gv[j]*a)*H + sv[j];
        }
    }
}

// ---- scan pass-3 (layers 0..2): replay (conv+dt recomputed) + gate, packed Y ----
__global__ void __launch_bounds__(256) k_scan3(
    const float* __restrict__ dbl, const float* __restrict__ xz,
    const float* __restrict__ cvw, const float* __restrict__ cvb,
    const float* __restrict__ A_log, const float* __restrict__ Dpar,
    const float* __restrict__ dtW, const float* __restrict__ dtbias,
    const float* __restrict__ Hinit, unsigned* __restrict__ Y)
{
    __shared__ float sbc[16*52];
    int tid = threadIdx.x;
    int c = blockIdx.y, b = blockIdx.z;
    int m0 = b*T_ + c*LCH;
    if(tid < 192){
        int t = tid/12, s = tid - t*12;
        *(float4*)(&sbc[t*52 + s*4]) = *(const float4*)(dbl + (size_t)(m0+t)*48 + s*4);
    }
    __syncthreads();
    int d = blockIdx.x*256 + tid;
    float xv[19];
    {
        int rbase = m0 - 3;
        bool mask0 = (c == 0);
#pragma unroll
        for(int j=0;j<19;j++)
            xv[j] = (mask0 && j<3) ? 0.f : xz[(size_t)(rbase+j)*DX + d];
    }
    float zvp[16];
#pragma unroll
    for(int t=0;t<16;t++) zvp[t] = xz[(size_t)(m0+t)*DX + DI + d];
    float4 w4 = *(const float4*)(cvw + d*4);
    float bias = cvb[d];
    float xhp[16];
#pragma unroll
    for(int t=0;t<16;t++){
        float a = bias + w4.x*xv[t] + w4.y*xv[t+1] + w4.z*xv[t+2] + w4.w*xv[t+3];
        xhp[t] = a * sigmoidf_(a);
    }
    float a_[16]; ld16(A_log + (size_t)d*16, a_);
#pragma unroll
    for(int n=0;n<16;n++) a_[n] = -__expf(a_[n]);
    float wr_[16]; ld16(dtW + (size_t)d*16, wr_);
    float bsv = dtbias[d];
    float st_[16]; ld16(Hinit + (((size_t)b*NC_ + c)*DI + d)*16, st_);
    float Dp = Dpar[d];
#pragma unroll 2
    for(int t=0;t<LCH;t++){
        int bt = m0 + t;
        float dl[16]; ld16(&sbc[t*52], dl);
        float bv[16]; ld16(&sbc[t*52 + 16], bv);
        float cv[16]; ld16(&sbc[t*52 + 32], cv);
        float pre = bsv;
#pragma unroll
        for(int r=0;r<16;r++) pre += dl[r]*wr_[r];
        float dtv = softplusf_(pre);
        float xhv = xhp[t];
        float dx = dtv*xhv;
        float y = 0.f;
#pragma unroll
        for(int n=0;n<16;n++){
            st_[n] = __expf(dtv*a_[n])*st_[n] + dx*bv[n];
            y += st_[n]*cv[n];
        }
        float zv = zvp[t];
        y += Dp*xhv;
        y = y * zv * sigmoidf_(zv);
        unsigned short hh = f2bf(y);
        unsigned short ll = f2bf(y - bf2f(hh));
        Y[(size_t)bt*DI + d] = (unsigned)hh | ((unsigned)ll << 16);
    }
}

// ---- scan pass-3 for LAST layer: fused with final output dot (writes d_out) ----
__global__ void __launch_bounds__(512) k_scan3o(
    const float* __restrict__ dbl, const float* __restrict__ xz,
    const float* __restrict__ cvw, const float* __restrict__ cvb,
    const float* __restrict__ A_log, const float* __restrict__ Dpar,
    const float* __restrict__ dtW, const float* __restrict__ dtbias,
    const float* __restrict__ Hinit, const float* __restrict__ cwc,
    float* __restrict__ out)
{
    __shared__ float sbc[16*52];
    __shared__ float sW[8][16];
    int tid = threadIdx.x;
    int c = blockIdx.x, b = blockIdx.y;
    int m0 = b*T_ + c*LCH;
    if(tid < 192){
        int t = tid/12, s = tid - t*12;
        *(float4*)(&sbc[t*52 + s*4]) = *(const float4*)(dbl + (size_t)(m0+t)*48 + s*4);
    }
    __syncthreads();
    int d = tid;
    int wave = tid >> 6, lane = tid & 63;
    float xv[19];
    {
        int rbase = m0 - 3;
        bool mask0 = (c == 0);
#pragma unroll
        for(int j=0;j<19;j++)
            xv[j] = (mask0 && j<3) ? 0.f : xz[(size_t)(rbase+j)*DX + d];
    }
    float zvp[16];
#pragma unroll
    for(int t=0;t<16;t++) zvp[t] = xz[(size_t)(m0+t)*DX + DI + d];
    float4 w4 = *(const float4*)(cvw + d*4);
    float bias = cvb[d];
    float xhp[16];
#pragma unroll
    for(int t=0;t<16;t++){
        float a = bias + w4.x*xv[t] + w4.y*xv[t+1] + w4.z*xv[t+2] + w4.w*xv[t+3];
        xhp[t] = a * sigmoidf_(a);
    }
    float a_[16]; ld16(A_log + (size_t)d*16, a_);
#pragma unroll
    for(int n=0;n<16;n++) a_[n] = -__expf(a_[n]);
    float wr_[16]; ld16(dtW + (size_t)d*16, wr_);
    float bsv = dtbias[d];
    float st_[16]; ld16(Hinit + (((size_t)b*NC_ + c)*DI + d)*16, st_);
    float Dp = Dpar[d];
    float cwv = cwc[d];
#pragma unroll 2
    for(int t=0;t<LCH;t++){
        float dl[16]; ld16(&sbc[t*52], dl);
        float bv[16]; ld16(&sbc[t*52 + 16], bv);
        float cv[16]; ld16(&sbc[t*52 + 32], cv);
        float pre = bsv;
#pragma unroll
        for(int r=0;r<16;r++) pre += dl[r]*wr_[r];
        float dtv = softplusf_(pre);
        float xhv = xhp[t];
        float dx = dtv*xhv;
        float y = 0.f;
#pragma unroll
        for(int n=0;n<16;n++){
            st_[n] = __expf(dtv*a_[n])*st_[n] + dx*bv[n];
            y += st_[n]*cv[n];
        }
        float zv = zvp[t];
        y += Dp*xhv;
        y = y * zv * sigmoidf_(zv);
        float s = y * cwv;
#pragma unroll
        for(int m=1;m<64;m<<=1) s += __shfl_xor(s,m);
        if(lane==0) sW[wave][t] = s;
    }
    __syncthreads();
    if(tid < 16){
        float s = 0.f;
#pragma unroll
        for(int w=0;w<8;w++) s += sW[w][tid];
        out[m0 + tid] = s;
    }
}

extern "C" void kernel_launch(void* const* d_in, const int* in_sizes, int n_in,
                              void* d_out, int out_size, void* d_ws, size_t ws_size,
                              hipStream_t stream){
    const float* x_src    = (const float*)d_in[0];
    const float* in_W     = (const float*)d_in[2];
    const float* norm_w   = (const float*)d_in[3];
    const float* norm_b   = (const float*)d_in[4];
    const float* inproj_W = (const float*)d_in[5];
    const float* conv_w   = (const float*)d_in[6];
    const float* conv_b   = (const float*)d_in[7];
    const float* xproj_W  = (const float*)d_in[8];
    const float* dtproj_W = (const float*)d_in[9];
    const float* dtproj_b = (const float*)d_in[10];
    const float* A_log    = (const float*)d_in[11];
    const float* D_param  = (const float*)d_in[12];
    const float* outproj_W= (const float*)d_in[13];
    const float* out_W    = (const float*)d_in[14];

    float* ws  = (float*)d_ws;
    float* res  = ws;                        // BT*DM
    float* xz   = res  + (size_t)BT_*DM;     // BT*DX
    float* dbl  = xz   + (size_t)BT_*DX;     // BT*48
    float* sdtb = dbl  + (size_t)BT_*48;     // B*NC*DI
    float* Sbuf = sdtb + (size_t)B_*NC_*DI;  // B*NC*DI*16
    float* Hbuf = Sbuf + (size_t)B_*NC_*DI*DS_;
    unsigned short* us = (unsigned short*)(Hbuf + (size_t)B_*NC_*DI*DS_);
    unsigned short* WhiIn  = us;                                  // NL*DX*DM
    unsigned short* WloIn  = WhiIn  + (size_t)NL*DX*DM;
    unsigned short* WhiOut = WloIn  + (size_t)NL*DX*DM;           // NL*DM*DI
    unsigned short* WloOut = WhiOut + (size_t)NL*DM*DI;
    unsigned short* WhiXp  = WloOut + (size_t)NL*DM*DI;           // NL*NO*DI
    unsigned short* WloXp  = WhiXp  + (size_t)NL*NO_*DI;
    unsigned short* hnhi   = WloXp  + (size_t)NL*NO_*DI;          // BT*DM
    unsigned short* hnlo   = hnhi   + (size_t)BT_*DM;
    unsigned*       ybuf   = (unsigned*)(hnlo + (size_t)BT_*DM);  // BT*DI
    float*          cwb    = (float*)(ybuf + (size_t)BT_*DI);     // DI

    k_init<<<NCVT + NINL, 256, 0, stream>>>(
        inproj_W,  WhiIn,  WloIn,
        outproj_W, WhiOut, WloOut,
        xproj_W,   WhiXp,  WloXp,
        outproj_W + (size_t)3*DM*DI, out_W, cwb,
        x_src, in_W, res, hnhi, hnlo, norm_w, norm_b);
    for(int i=0;i<NL;i++){
        k_gemm_bf3<64,128><<<dim3(DX/128, BT_/64), 256, 0, stream>>>(
            hnhi, hnlo, WhiIn + (size_t)i*DX*DM, WloIn + (size_t)i*DX*DM, xz, BT_, DX, DM);
        k_convxp2<<<BT_/LCH, 512, 0, stream>>>(xz, conv_w + i*DI*4, conv_b + i*DI,
            WhiXp + (size_t)i*NO_*DI, WloXp + (size_t)i*NO_*DI,
            dtproj_W + (size_t)i*DI*DR_, dtproj_b + i*DI,
            A_log + (size_t)i*DI*DS_, dbl, Sbuf, sdtb);
        k_scan2<<<B_*DI*DS_/128, 128, 0, stream>>>(Sbuf, sdtb, A_log + (size_t)i*DI*DS_, Hbuf);
        if(i < NL-1){
            k_scan3<<<dim3(2, NC_, B_), 256, 0, stream>>>(dbl, xz,
                conv_w + i*DI*4, conv_b + i*DI,
                A_log + (size_t)i*DI*DS_, D_param + i*DI,
                dtproj_W + (size_t)i*DI*DR_, dtproj_b + i*DI, Hbuf, ybuf);
            k_gemm_pk_res<<<dim3(DM/64, BT_/64), 256, 0, stream>>>(
                ybuf, WhiOut + (size_t)i*DM*DI, WloOut + (size_t)i*DM*DI, res);
            k_resln<<<BT_/4, 256, 0, stream>>>(res, hnhi, hnlo,
                norm_w + (i+1)*DM, norm_b + (i+1)*DM);
        } else {
            k_scan3o<<<dim3(NC_, B_), 512, 0, stream>>>(dbl, xz,
                conv_w + i*DI*4, conv_b + i*DI,
                A_log + (size_t)i*DI*DS_, D_param + i*DI,
                dtproj_W + (size_t)i*DI*DR_, dtproj_b + i*DI, Hbuf, cwb,
                (float*)d_out);
        }
    }
}